// Round 6
// baseline (3221.915 us; speedup 1.0000x reference)
//
#include <hip/hip_runtime.h>
#include <hip/hip_bf16.h>
#include <cstdint>

// ReportDecoder: B=512,S=49,E=1024,H=1024,V2=16,L=64,T=48, D_IN=1105
// Round 6: BISECT. Compute = verbatim round-3 k_steps inner loop (proven pass).
// Sync = two-level hierarchical RMW barrier (r3 semantics, 8 XCD-local arrival
// chains + global chain + single release point), strictly stronger fences.

typedef __bf16 bf16_t;
typedef bf16_t bf16x8 __attribute__((ext_vector_type(8)));
typedef bf16_t bf16x4 __attribute__((ext_vector_type(4)));
typedef float  f32x4  __attribute__((ext_vector_type(4)));
typedef float  f32x16 __attribute__((ext_vector_type(16)));

#define Bn   512
#define Sn   49
#define En   1024
#define Hn   1024
#define Ln   64
#define Tn   48
#define DINn 1105
#define NOn  1090

#define BM   64
#define LDSP 72     // padded K-stride for 64-wide tiles in init/out GEMMs

__device__ __forceinline__ float sigm(float x){ return 1.0f / (1.0f + __expf(-x)); }

// ---------- image mean ----------
__global__ __launch_bounds__(256) void k_mean(const float* __restrict__ image,
                                              bf16_t* __restrict__ imb){
  int b  = blockIdx.x;
  int e0 = threadIdx.x * 4;
  const float* p = image + (size_t)b * (Sn * En) + e0;
  float4 acc = make_float4(0.f, 0.f, 0.f, 0.f);
  for (int s = 0; s < Sn; ++s){
    float4 v = *reinterpret_cast<const float4*>(p + (size_t)s * En);
    acc.x += v.x; acc.y += v.y; acc.z += v.z; acc.w += v.w;
  }
  const float inv = 1.0f / 49.0f;
  bf16x4 o;
  o[0] = (bf16_t)(acc.x * inv); o[1] = (bf16_t)(acc.y * inv);
  o[2] = (bf16_t)(acc.z * inv); o[3] = (bf16_t)(acc.w * inv);
  *reinterpret_cast<bf16x4*>(imb + (size_t)b * En + e0) = o;
}

// ---------- fp32 -> bf16 conversions ----------
__global__ __launch_bounds__(256) void k_convert(
    const float* __restrict__ w_hh,  const float* __restrict__ fc_h_w,
    const float* __restrict__ fc_m_w,const float* __restrict__ fc_w,
    const float* __restrict__ label, const float* __restrict__ w_ih,
    bf16_t* __restrict__ whhb,  bf16_t* __restrict__ fchwb,
    bf16_t* __restrict__ fcmwb, bf16_t* __restrict__ fcwb,
    bf16_t* __restrict__ labelb,bf16_t* __restrict__ wimgb,
    bf16_t* __restrict__ wlabb){
  const int NV0 = 4096 * 1024 / 4;
  const int NV1 = NV0 + 1024 * 1024 / 4;
  const int NV2 = NV1 + 1024 * 1024 / 4;
  const int NV3 = NV2 + 1090 * 1024 / 4;
  const int NV4 = NV3 + 512 * 49 * 64 / 4;
  const int NS5 = NV4 + 4096 * 1024;
  const int NS6 = NS5 + 4096 * 64;
  int stride = gridDim.x * blockDim.x;
  for (int i = blockIdx.x * blockDim.x + threadIdx.x; i < NS6; i += stride){
    if (i < NV4){
      const float* src; bf16_t* dst; int j;
      if      (i < NV0){ src = w_hh;   dst = whhb;  j = i; }
      else if (i < NV1){ src = fc_h_w; dst = fchwb; j = i - NV0; }
      else if (i < NV2){ src = fc_m_w; dst = fcmwb; j = i - NV1; }
      else if (i < NV3){ src = fc_w;   dst = fcwb;  j = i - NV2; }
      else             { src = label;  dst = labelb;j = i - NV3; }
      float4 v = *reinterpret_cast<const float4*>(src + (size_t)j * 4);
      bf16x4 o;
      o[0] = (bf16_t)v.x; o[1] = (bf16_t)v.y; o[2] = (bf16_t)v.z; o[3] = (bf16_t)v.w;
      *reinterpret_cast<bf16x4*>(dst + (size_t)j * 4) = o;
    } else if (i < NS5){
      int j = i - NV4; int n = j >> 10, k = j & 1023;
      wimgb[j] = (bf16_t)w_ih[(size_t)n * DINn + k];
    } else {
      int j = i - NS5; int n = j >> 6, k = j & 63;
      wlabb[j] = (bf16_t)w_ih[(size_t)n * DINn + 1041 + k];
    }
  }
}

// ---------- xconst pre-pass + barrier-state zero ----------
__global__ __launch_bounds__(256) void k_vpc(const float* __restrict__ w_ih,
                                             const float* __restrict__ vp,
                                             const float* __restrict__ b_ih,
                                             const float* __restrict__ b_hh,
                                             float* __restrict__ xconst,
                                             unsigned* __restrict__ bar){
  if (blockIdx.x < 4) bar[blockIdx.x * 256 + threadIdx.x] = 0u;  // 1024 u32
  int idx = blockIdx.x * 256 + threadIdx.x;
  int b = idx >> 12, n = idx & 4095;
  float acc = b_ih[n] + b_hh[n];
  const float* w = w_ih + (size_t)n * DINn + En;
  const float* v = vp + b * 16;
  #pragma unroll
  for (int j = 0; j < 16; ++j) acc += v[j] * w[j];
  xconst[idx] = acc;
}

// ---------- shared GEMM helpers (64x128 tile, 4 waves, 16x16x32) ----------
__device__ __forceinline__ void stageA(bf16_t* sA, const bf16_t* gptr, int ld, int tid){
  #pragma unroll
  for (int i = 0; i < 2; ++i){
    int idx = tid + i * 256;
    int r = idx >> 3, v = idx & 7;
    *reinterpret_cast<bf16x8*>(sA + r * LDSP + v * 8) =
      *reinterpret_cast<const bf16x8*>(gptr + (size_t)r * ld + v * 8);
  }
}

__device__ __forceinline__ void mma_tile(const bf16_t* sA, const bf16_t* sB,
                                         f32x4 (&acc)[4][2], int lane, int w){
  int lr = lane & 15;
  int lk = (lane >> 4) * 8;
  #pragma unroll
  for (int kk = 0; kk < 2; ++kk){
    bf16x8 a[4], bb[2];
    #pragma unroll
    for (int mi = 0; mi < 4; ++mi)
      a[mi] = *reinterpret_cast<const bf16x8*>(sA + (mi * 16 + lr) * LDSP + kk * 32 + lk);
    #pragma unroll
    for (int ni = 0; ni < 2; ++ni)
      bb[ni] = *reinterpret_cast<const bf16x8*>(sB + (w * 32 + ni * 16 + lr) * LDSP + kk * 32 + lk);
    #pragma unroll
    for (int mi = 0; mi < 4; ++mi)
      #pragma unroll
      for (int ni = 0; ni < 2; ++ni)
        acc[mi][ni] = __builtin_amdgcn_mfma_f32_16x16x32_bf16(a[mi], bb[ni], acc[mi][ni], 0, 0, 0);
  }
}

// ---------- init GEMM: h0, m0, xconst += im@Wimg^T ----------
__global__ __launch_bounds__(256) void k_init_gemm(
    const bf16_t* __restrict__ imb,  const bf16_t* __restrict__ fchw,
    const bf16_t* __restrict__ fcmw, const bf16_t* __restrict__ wimg,
    const float* __restrict__ fc_h_b,const float* __restrict__ fc_m_b,
    bf16_t* __restrict__ h0, float* __restrict__ m0, float* __restrict__ xconst){
  __shared__ __align__(16) unsigned char smem[(BM + 128) * LDSP * 2];
  bf16_t* sA = (bf16_t*)smem;
  bf16_t* sB = (bf16_t*)(smem + BM * LDSP * 2);
  int tid = threadIdx.x;
  int cb = blockIdx.x, rb = blockIdx.y;
  int nBase = cb * 128;
  const bf16_t* Bsrc; int nOff;
  if      (nBase < 1024){ Bsrc = fchw; nOff = nBase; }
  else if (nBase < 2048){ Bsrc = fcmw; nOff = nBase - 1024; }
  else                  { Bsrc = wimg; nOff = nBase - 2048; }

  f32x4 acc[4][2] = {};
  int lane = tid & 63, w = tid >> 6;
  for (int kt = 0; kt < 16; ++kt){
    stageA(sA, imb + (size_t)(rb * 64) * 1024 + kt * 64, 1024, tid);
    #pragma unroll
    for (int i = 0; i < 4; ++i){
      int idx = tid + i * 256;
      int r = idx >> 3, v = idx & 7;
      *reinterpret_cast<bf16x8*>(sB + r * LDSP + v * 8) =
        *reinterpret_cast<const bf16x8*>(Bsrc + (size_t)(nOff + r) * 1024 + kt * 64 + v * 8);
    }
    __syncthreads();
    mma_tile(sA, sB, acc, lane, w);
    __syncthreads();
  }
  int lr = lane & 15, lg = lane >> 4;
  #pragma unroll
  for (int mi = 0; mi < 4; ++mi)
    #pragma unroll
    for (int ni = 0; ni < 2; ++ni)
      #pragma unroll
      for (int r = 0; r < 4; ++r){
        int ng   = nBase + w * 32 + ni * 16 + lr;
        int rowg = rb * 64 + mi * 16 + lg * 4 + r;
        float v = acc[mi][ni][r];
        if (ng < 1024){
          h0[(size_t)rowg * 1024 + ng] = (bf16_t)tanhf(v + fc_h_b[ng]);
        } else if (ng < 2048){
          int n = ng - 1024;
          m0[(size_t)rowg * 1024 + n] = tanhf(v + fc_m_b[n]);
        } else {
          int n = ng - 2048;
          xconst[(size_t)rowg * 4096 + n] += v;
        }
      }
}

// ---------- two-level hierarchical grid barrier (r3 semantics, cheaper) ----------
// bar[0]=gen, bar[320]=gcnt, bar[384+32x]=xcnt[x] (x = blk&7, XCD-local chain).
__device__ __forceinline__ void grid_barrier(unsigned* __restrict__ bar, unsigned step){
  __threadfence();            // release: every thread drains its h stores
  __syncthreads();
  if (threadIdx.x == 0){
    unsigned x = (unsigned)blockIdx.x & 7u;
    unsigned* xcnt = bar + 384 + 32 * x;
    unsigned* gcnt = bar + 320;
    unsigned* gen  = bar;
    if (__hip_atomic_fetch_add(xcnt, 1u, __ATOMIC_ACQ_REL, __HIP_MEMORY_SCOPE_AGENT) == 31u){
      __hip_atomic_store(xcnt, 0u, __ATOMIC_RELAXED, __HIP_MEMORY_SCOPE_AGENT);
      if (__hip_atomic_fetch_add(gcnt, 1u, __ATOMIC_ACQ_REL, __HIP_MEMORY_SCOPE_AGENT) == 7u){
        __hip_atomic_store(gcnt, 0u, __ATOMIC_RELAXED, __HIP_MEMORY_SCOPE_AGENT);
        __hip_atomic_store(gen, step + 1u, __ATOMIC_RELEASE, __HIP_MEMORY_SCOPE_AGENT);
      }
    }
    while (__hip_atomic_load(gen, __ATOMIC_ACQUIRE, __HIP_MEMORY_SCOPE_AGENT) <= step)
      __builtin_amdgcn_s_sleep(2);
  }
  __syncthreads();
  __threadfence();            // acquire: every wave invalidates before its own loads
}

// ---------- persistent kernel: all 48 LSTM steps (compute verbatim r3) ----------
__global__ __launch_bounds__(256, 1) void k_steps(
    bf16_t* hs,                         // (49, 512, 1024); hs[0]=h0
    const bf16_t* __restrict__ whh,     // (4096, 1024)
    const bf16_t* __restrict__ wlab,    // (4096, 64)
    const bf16_t* __restrict__ labelb,  // (512, 49, 64)
    const float*  __restrict__ xconst,  // (512, 4096)
    const float*  __restrict__ w_ih,    // (4096, 1105), begin col 1040
    const float*  __restrict__ m_init,  // (512, 1024)
    unsigned* __restrict__ bar){
  __shared__ __align__(16) bf16_t sB[64 * 1024];   // 128 KB, swizzled
  __shared__ __align__(16) bf16_t sLab[64 * 64];   // 8 KB, swizzled
  int tid  = threadIdx.x;
  int blk  = blockIdx.x;
  int xcd  = blk & 7;
  int rb   = xcd >> 1;
  int cb   = ((blk >> 3) << 1) | (xcd & 1);
  int lane = tid & 63, w = tid >> 6;
  int l31  = lane & 31;
  int h6   = lane >> 5;
  int b5   = (lane >> 4) & 1;

  // stage resident W slices (swizzled: unit v -> v ^ sw(row), sw = (r ^ r>>3)&7)
  for (int i = tid; i < 8192; i += 256){
    int r = i >> 7, v = i & 127;
    int g = r >> 4, hj = r & 15;
    int sw = (r ^ (r >> 3)) & 7;
    *reinterpret_cast<bf16x8*>(sB + r * 1024 + (v ^ sw) * 8) =
      *reinterpret_cast<const bf16x8*>(whh + (size_t)(g * 1024 + cb * 16 + hj) * 1024 + v * 8);
  }
  for (int i = tid; i < 512; i += 256){
    int r = i >> 3, v = i & 7;
    int g = r >> 4, hj = r & 15;
    int sw = (r ^ (r >> 3)) & 7;
    *reinterpret_cast<bf16x8*>(sLab + r * 64 + (v ^ sw) * 8) =
      *reinterpret_cast<const bf16x8*>(wlab + (size_t)(g * 1024 + cb * 16 + hj) * 64 + v * 8);
  }

  // per-lane constants
  int hcolG = cb * 16 + (lane & 15);
  int row0w = rb * 128 + w * 32;
  float xc[4][8], mreg[8], wb[4];
  #pragma unroll
  for (int g = 0; g < 4; ++g)
    wb[g] = w_ih[(size_t)(g * 1024 + hcolG) * DINn + 1040];
  #pragma unroll
  for (int qi = 0; qi < 8; ++qi){
    int row_l = (qi & 3) + 8 * (qi >> 2) + 16 * b5 + 4 * h6;
    int rowG  = row0w + row_l;
    mreg[qi] = m_init[(size_t)rowG * 1024 + hcolG];
    #pragma unroll
    for (int g = 0; g < 4; ++g)
      xc[g][qi] = xconst[(size_t)rowG * 4096 + g * 1024 + hcolG];
  }
  __syncthreads();

  // LDS read bases + per-frag swizzle keys (sw(row+32) = sw(row)^4)
  int sw0 = (l31 ^ (l31 >> 3)) & 7;
  int sw1 = sw0 ^ 4;
  const bf16_t* sb0 = sB + (size_t)l31 * 1024;
  const bf16_t* sb1 = sB + (size_t)(32 + l31) * 1024;
  const bf16_t* sl0 = sLab + (size_t)l31 * 64;
  const bf16_t* sl1 = sLab + (size_t)(32 + l31) * 64;
  const bf16_t* aBase = hs + (size_t)(row0w + l31) * Hn + h6 * 8;
  const bf16_t* lBase = labelb + (size_t)(row0w + l31) * (Sn * Ln) + h6 * 8;

  for (int t = 0; t < Tn; ++t){
    const bf16_t* aptr = aBase + (size_t)t * (Bn * Hn);
    f32x16 acc[2] = {};
    #pragma unroll 4
    for (int kt = 0; kt < 16; ++kt){
      int kb = kt * 64;
      bf16x8 a[4], b0[4], b1[4];
      #pragma unroll
      for (int ks = 0; ks < 4; ++ks){
        a[ks]  = *reinterpret_cast<const bf16x8*>(aptr + kb + ks * 16);
        int u  = kt * 8 + ks * 2 + h6;
        b0[ks] = *reinterpret_cast<const bf16x8*>(sb0 + (u ^ sw0) * 8);
        b1[ks] = *reinterpret_cast<const bf16x8*>(sb1 + (u ^ sw1) * 8);
      }
      #pragma unroll
      for (int ks = 0; ks < 4; ++ks){
        acc[0] = __builtin_amdgcn_mfma_f32_32x32x16_bf16(a[ks], b0[ks], acc[0], 0, 0, 0);
        acc[1] = __builtin_amdgcn_mfma_f32_32x32x16_bf16(a[ks], b1[ks], acc[1], 0, 0, 0);
      }
    }
    if (t > 0){
      const bf16_t* lp = lBase + (size_t)(t - 1) * 64;
      bf16x8 a[4], b0[4], b1[4];
      #pragma unroll
      for (int ks = 0; ks < 4; ++ks){
        a[ks]  = *reinterpret_cast<const bf16x8*>(lp + ks * 16);
        int u  = ks * 2 + h6;
        b0[ks] = *reinterpret_cast<const bf16x8*>(sl0 + (u ^ sw0) * 8);
        b1[ks] = *reinterpret_cast<const bf16x8*>(sl1 + (u ^ sw1) * 8);
      }
      #pragma unroll
      for (int ks = 0; ks < 4; ++ks){
        acc[0] = __builtin_amdgcn_mfma_f32_32x32x16_bf16(a[ks], b0[ks], acc[0], 0, 0, 0);
        acc[1] = __builtin_amdgcn_mfma_f32_32x32x16_bf16(a[ks], b1[ks], acc[1], 0, 0, 0);
      }
    }

    // gate exchange: partner lane^16 holds the other two gates for same (rows, hcol)
    float oth0[16], oth1[16];
    #pragma unroll
    for (int q = 0; q < 16; ++q){
      oth0[q] = __shfl_xor(acc[0][q], 16, 64);
      oth1[q] = __shfl_xor(acc[1][q], 16, 64);
    }
    bf16_t* hO = hs + (size_t)(t + 1) * (Bn * Hn);
    #pragma unroll
    for (int qi = 0; qi < 8; ++qi){
      float v0, v1, v2, v3;
      if (b5 == 0){ v0 = acc[0][qi];   v1 = oth0[qi];   v2 = acc[1][qi];   v3 = oth1[qi]; }
      else        { v0 = oth0[qi + 8]; v1 = acc[0][qi + 8]; v2 = oth1[qi + 8]; v3 = acc[1][qi + 8]; }
      float gi = v0 + xc[0][qi];
      float gf = v1 + xc[1][qi];
      float gg = v2 + xc[2][qi];
      float go = v3 + xc[3][qi];
      if (t == 0){ gi += wb[0]; gf += wb[1]; gg += wb[2]; go += wb[3]; }
      float mn = sigm(gf) * mreg[qi] + sigm(gi) * tanhf(gg);
      mreg[qi] = mn;
      float hn = sigm(go) * tanhf(mn);
      int row_l = (qi & 3) + 8 * (qi >> 2) + 16 * b5 + 4 * h6;
      hO[(size_t)(row0w + row_l) * 1024 + hcolG] = (bf16_t)hn;
    }
    if (t < Tn - 1)
      grid_barrier(bar, (unsigned)t);
  }
}

// ---------- batched out GEMM + activations + mask + scatter ----------
__global__ __launch_bounds__(256) void k_out(
    const bf16_t* __restrict__ h,      // hs + 512*1024: 24576 x 1024
    const bf16_t* __restrict__ fcwb,
    const float* __restrict__ fc_b, const int* __restrict__ length,
    float* __restrict__ out){
  __shared__ __align__(16) unsigned char smem[(BM + 128) * LDSP * 2];
  bf16_t* sA = (bf16_t*)smem;
  bf16_t* sB = (bf16_t*)(smem + BM * LDSP * 2);
  int tid = threadIdx.x;
  int cb = blockIdx.x, rb = blockIdx.y;
  f32x4 acc[4][2] = {};
  int lane = tid & 63, w = tid >> 6;
  for (int kt = 0; kt < 16; ++kt){
    stageA(sA, h + (size_t)(rb * 64) * 1024 + kt * 64, 1024, tid);
    #pragma unroll
    for (int i = 0; i < 4; ++i){
      int idx = tid + i * 256;
      int r = idx >> 3, v = idx & 7;
      int n = cb * 128 + r;
      bf16x8 val = {};
      if (n < NOn)
        val = *reinterpret_cast<const bf16x8*>(fcwb + (size_t)n * 1024 + kt * 64 + v * 8);
      *reinterpret_cast<bf16x8*>(sB + r * LDSP + v * 8) = val;
    }
    __syncthreads();
    mma_tile(sA, sB, acc, lane, w);
    __syncthreads();
  }
  int lr = lane & 15, lg = lane >> 4;
  #pragma unroll
  for (int mi = 0; mi < 4; ++mi)
    #pragma unroll
    for (int ni = 0; ni < 2; ++ni)
      #pragma unroll
      for (int r = 0; r < 4; ++r){
        int ng = cb * 128 + w * 32 + ni * 16 + lr;
        if (ng >= NOn) continue;
        int rg = rb * 64 + mi * 16 + lg * 4 + r;
        int tt = rg >> 9, b = rg & 511;
        float v = acc[mi][ni][r] + fc_b[ng];
        float mask = (tt < length[b]) ? 1.0f : 0.0f;
        if      (ng < 64)    out[(size_t)rg * 64 + ng] = sigm(v) * mask;
        else if (ng < 1088)  out[(size_t)1572864 + (size_t)rg * 1024 + (ng - 64)] = fmaxf(v, 0.f) * mask;
        else if (ng == 1088) out[(size_t)26738688 + rg] = sigm(v) * mask;
        else                 out[(size_t)26763264 + rg] = __expf(v) * mask;
      }
}

extern "C" void kernel_launch(void* const* d_in, const int* in_sizes, int n_in,
                              void* d_out, int out_size, void* d_ws, size_t ws_size,
                              hipStream_t stream){
  const float* image  = (const float*)d_in[0];
  const float* vp     = (const float*)d_in[1];
  const float* label  = (const float*)d_in[2];
  const int*   length = (const int*)  d_in[3];
  const float* fc_h_w = (const float*)d_in[4];
  const float* fc_h_b = (const float*)d_in[5];
  const float* fc_m_w = (const float*)d_in[6];
  const float* fc_m_b = (const float*)d_in[7];
  const float* w_ih   = (const float*)d_in[8];
  const float* w_hh   = (const float*)d_in[9];
  const float* b_ih   = (const float*)d_in[10];
  const float* b_hh   = (const float*)d_in[11];
  const float* fc_w   = (const float*)d_in[12];
  const float* fc_b   = (const float*)d_in[13];
  float* out = (float*)d_out;

  char* ws = (char*)d_ws;
  bf16_t* imb    = (bf16_t*)(ws + 0);           // 1 MB
  bf16_t* hs     = (bf16_t*)(ws + 1048576);     // 51.4 MB
  float*  m      = (float*) (ws + 52428800);    // 2 MB
  float*  xconst = (float*) (ws + 54525952);    // 8 MB
  bf16_t* whhb   = (bf16_t*)(ws + 62914560);    // 8 MB
  bf16_t* wimgb  = (bf16_t*)(ws + 71303168);    // 8 MB
  bf16_t* wlabb  = (bf16_t*)(ws + 79691776);    // 0.5 MB
  bf16_t* fchwb  = (bf16_t*)(ws + 80216064);    // 2 MB
  bf16_t* fcmwb  = (bf16_t*)(ws + 82313216);    // 2 MB
  bf16_t* fcwb   = (bf16_t*)(ws + 84410368);    // 2.2 MB
  bf16_t* labelb = (bf16_t*)(ws + 86642688);    // 3.2 MB (ends 89853952)
  unsigned* bar  = (unsigned*)(ws + 89853952);  // 4 KB barrier state

  k_mean   <<<dim3(512),  dim3(256), 0, stream>>>(image, imb);
  k_convert<<<dim3(2048), dim3(256), 0, stream>>>(w_hh, fc_h_w, fc_m_w, fc_w, label, w_ih,
                                                  whhb, fchwb, fcmwb, fcwb, labelb, wimgb, wlabb);
  k_vpc    <<<dim3(8192), dim3(256), 0, stream>>>(w_ih, vp, b_ih, b_hh, xconst, bar);
  k_init_gemm<<<dim3(48, 8), dim3(256), 0, stream>>>(imb, fchwb, fcmwb, wimgb,
                                                     fc_h_b, fc_m_b, hs, m, xconst);

  bf16_t* hs_p = hs;
  const bf16_t* whh_p = whhb;
  const bf16_t* wlab_p = wlabb;
  const bf16_t* labelb_p = labelb;
  const float* xconst_p = xconst;
  const float* wih_p = w_ih;
  const float* m_p = m;
  unsigned* bar_p = bar;
  void* kargs[8] = { (void*)&hs_p, (void*)&whh_p, (void*)&wlab_p, (void*)&labelb_p,
                     (void*)&xconst_p, (void*)&wih_p, (void*)&m_p, (void*)&bar_p };
  (void)hipLaunchCooperativeKernel(reinterpret_cast<void*>(k_steps),
                                   dim3(256), dim3(256), kargs, 0, stream);

  k_out<<<dim3(9, 384), dim3(256), 0, stream>>>(hs + (size_t)512 * 1024, fcwb, fc_b, length, out);
}

// Round 7
// 2022.956 us; speedup vs baseline: 1.5927x; 1.5927x over previous
//
#include <hip/hip_runtime.h>
#include <hip/hip_bf16.h>
#include <cstdint>

// ReportDecoder: B=512,S=49,E=1024,H=1024,V2=16,L=64,T=48, D_IN=1105
// Round 7: r6 with the barrier replaced by r3-protocol + two-level arrival:
//   relaxed RMW arrival (8 XCD-local chains of 32 -> 1 chain of 8),
//   single RELEASE store of gen, RELAXED polls, wave0-only acquire fence.
// (r3 passed twice with this exact fence structure; arrival cost 30us -> ~4us.)

typedef __bf16 bf16_t;
typedef bf16_t bf16x8 __attribute__((ext_vector_type(8)));
typedef bf16_t bf16x4 __attribute__((ext_vector_type(4)));
typedef float  f32x4  __attribute__((ext_vector_type(4)));
typedef float  f32x16 __attribute__((ext_vector_type(16)));

#define Bn   512
#define Sn   49
#define En   1024
#define Hn   1024
#define Ln   64
#define Tn   48
#define DINn 1105
#define NOn  1090

#define BM   64
#define LDSP 72     // padded K-stride for 64-wide tiles in init/out GEMMs

__device__ __forceinline__ float sigm(float x){ return 1.0f / (1.0f + __expf(-x)); }

// ---------- image mean ----------
__global__ __launch_bounds__(256) void k_mean(const float* __restrict__ image,
                                              bf16_t* __restrict__ imb){
  int b  = blockIdx.x;
  int e0 = threadIdx.x * 4;
  const float* p = image + (size_t)b * (Sn * En) + e0;
  float4 acc = make_float4(0.f, 0.f, 0.f, 0.f);
  for (int s = 0; s < Sn; ++s){
    float4 v = *reinterpret_cast<const float4*>(p + (size_t)s * En);
    acc.x += v.x; acc.y += v.y; acc.z += v.z; acc.w += v.w;
  }
  const float inv = 1.0f / 49.0f;
  bf16x4 o;
  o[0] = (bf16_t)(acc.x * inv); o[1] = (bf16_t)(acc.y * inv);
  o[2] = (bf16_t)(acc.z * inv); o[3] = (bf16_t)(acc.w * inv);
  *reinterpret_cast<bf16x4*>(imb + (size_t)b * En + e0) = o;
}

// ---------- fp32 -> bf16 conversions ----------
__global__ __launch_bounds__(256) void k_convert(
    const float* __restrict__ w_hh,  const float* __restrict__ fc_h_w,
    const float* __restrict__ fc_m_w,const float* __restrict__ fc_w,
    const float* __restrict__ label, const float* __restrict__ w_ih,
    bf16_t* __restrict__ whhb,  bf16_t* __restrict__ fchwb,
    bf16_t* __restrict__ fcmwb, bf16_t* __restrict__ fcwb,
    bf16_t* __restrict__ labelb,bf16_t* __restrict__ wimgb,
    bf16_t* __restrict__ wlabb){
  const int NV0 = 4096 * 1024 / 4;
  const int NV1 = NV0 + 1024 * 1024 / 4;
  const int NV2 = NV1 + 1024 * 1024 / 4;
  const int NV3 = NV2 + 1090 * 1024 / 4;
  const int NV4 = NV3 + 512 * 49 * 64 / 4;
  const int NS5 = NV4 + 4096 * 1024;
  const int NS6 = NS5 + 4096 * 64;
  int stride = gridDim.x * blockDim.x;
  for (int i = blockIdx.x * blockDim.x + threadIdx.x; i < NS6; i += stride){
    if (i < NV4){
      const float* src; bf16_t* dst; int j;
      if      (i < NV0){ src = w_hh;   dst = whhb;  j = i; }
      else if (i < NV1){ src = fc_h_w; dst = fchwb; j = i - NV0; }
      else if (i < NV2){ src = fc_m_w; dst = fcmwb; j = i - NV1; }
      else if (i < NV3){ src = fc_w;   dst = fcwb;  j = i - NV2; }
      else             { src = label;  dst = labelb;j = i - NV3; }
      float4 v = *reinterpret_cast<const float4*>(src + (size_t)j * 4);
      bf16x4 o;
      o[0] = (bf16_t)v.x; o[1] = (bf16_t)v.y; o[2] = (bf16_t)v.z; o[3] = (bf16_t)v.w;
      *reinterpret_cast<bf16x4*>(dst + (size_t)j * 4) = o;
    } else if (i < NS5){
      int j = i - NV4; int n = j >> 10, k = j & 1023;
      wimgb[j] = (bf16_t)w_ih[(size_t)n * DINn + k];
    } else {
      int j = i - NS5; int n = j >> 6, k = j & 63;
      wlabb[j] = (bf16_t)w_ih[(size_t)n * DINn + 1041 + k];
    }
  }
}

// ---------- xconst pre-pass + barrier-state zero ----------
__global__ __launch_bounds__(256) void k_vpc(const float* __restrict__ w_ih,
                                             const float* __restrict__ vp,
                                             const float* __restrict__ b_ih,
                                             const float* __restrict__ b_hh,
                                             float* __restrict__ xconst,
                                             unsigned* __restrict__ bar){
  if (blockIdx.x < 4) bar[blockIdx.x * 256 + threadIdx.x] = 0u;  // 1024 u32
  int idx = blockIdx.x * 256 + threadIdx.x;
  int b = idx >> 12, n = idx & 4095;
  float acc = b_ih[n] + b_hh[n];
  const float* w = w_ih + (size_t)n * DINn + En;
  const float* v = vp + b * 16;
  #pragma unroll
  for (int j = 0; j < 16; ++j) acc += v[j] * w[j];
  xconst[idx] = acc;
}

// ---------- shared GEMM helpers (64x128 tile, 4 waves, 16x16x32) ----------
__device__ __forceinline__ void stageA(bf16_t* sA, const bf16_t* gptr, int ld, int tid){
  #pragma unroll
  for (int i = 0; i < 2; ++i){
    int idx = tid + i * 256;
    int r = idx >> 3, v = idx & 7;
    *reinterpret_cast<bf16x8*>(sA + r * LDSP + v * 8) =
      *reinterpret_cast<const bf16x8*>(gptr + (size_t)r * ld + v * 8);
  }
}

__device__ __forceinline__ void mma_tile(const bf16_t* sA, const bf16_t* sB,
                                         f32x4 (&acc)[4][2], int lane, int w){
  int lr = lane & 15;
  int lk = (lane >> 4) * 8;
  #pragma unroll
  for (int kk = 0; kk < 2; ++kk){
    bf16x8 a[4], bb[2];
    #pragma unroll
    for (int mi = 0; mi < 4; ++mi)
      a[mi] = *reinterpret_cast<const bf16x8*>(sA + (mi * 16 + lr) * LDSP + kk * 32 + lk);
    #pragma unroll
    for (int ni = 0; ni < 2; ++ni)
      bb[ni] = *reinterpret_cast<const bf16x8*>(sB + (w * 32 + ni * 16 + lr) * LDSP + kk * 32 + lk);
    #pragma unroll
    for (int mi = 0; mi < 4; ++mi)
      #pragma unroll
      for (int ni = 0; ni < 2; ++ni)
        acc[mi][ni] = __builtin_amdgcn_mfma_f32_16x16x32_bf16(a[mi], bb[ni], acc[mi][ni], 0, 0, 0);
  }
}

// ---------- init GEMM: h0, m0, xconst += im@Wimg^T ----------
__global__ __launch_bounds__(256) void k_init_gemm(
    const bf16_t* __restrict__ imb,  const bf16_t* __restrict__ fchw,
    const bf16_t* __restrict__ fcmw, const bf16_t* __restrict__ wimg,
    const float* __restrict__ fc_h_b,const float* __restrict__ fc_m_b,
    bf16_t* __restrict__ h0, float* __restrict__ m0, float* __restrict__ xconst){
  __shared__ __align__(16) unsigned char smem[(BM + 128) * LDSP * 2];
  bf16_t* sA = (bf16_t*)smem;
  bf16_t* sB = (bf16_t*)(smem + BM * LDSP * 2);
  int tid = threadIdx.x;
  int cb = blockIdx.x, rb = blockIdx.y;
  int nBase = cb * 128;
  const bf16_t* Bsrc; int nOff;
  if      (nBase < 1024){ Bsrc = fchw; nOff = nBase; }
  else if (nBase < 2048){ Bsrc = fcmw; nOff = nBase - 1024; }
  else                  { Bsrc = wimg; nOff = nBase - 2048; }

  f32x4 acc[4][2] = {};
  int lane = tid & 63, w = tid >> 6;
  for (int kt = 0; kt < 16; ++kt){
    stageA(sA, imb + (size_t)(rb * 64) * 1024 + kt * 64, 1024, tid);
    #pragma unroll
    for (int i = 0; i < 4; ++i){
      int idx = tid + i * 256;
      int r = idx >> 3, v = idx & 7;
      *reinterpret_cast<bf16x8*>(sB + r * LDSP + v * 8) =
        *reinterpret_cast<const bf16x8*>(Bsrc + (size_t)(nOff + r) * 1024 + kt * 64 + v * 8);
    }
    __syncthreads();
    mma_tile(sA, sB, acc, lane, w);
    __syncthreads();
  }
  int lr = lane & 15, lg = lane >> 4;
  #pragma unroll
  for (int mi = 0; mi < 4; ++mi)
    #pragma unroll
    for (int ni = 0; ni < 2; ++ni)
      #pragma unroll
      for (int r = 0; r < 4; ++r){
        int ng   = nBase + w * 32 + ni * 16 + lr;
        int rowg = rb * 64 + mi * 16 + lg * 4 + r;
        float v = acc[mi][ni][r];
        if (ng < 1024){
          h0[(size_t)rowg * 1024 + ng] = (bf16_t)tanhf(v + fc_h_b[ng]);
        } else if (ng < 2048){
          int n = ng - 1024;
          m0[(size_t)rowg * 1024 + n] = tanhf(v + fc_m_b[n]);
        } else {
          int n = ng - 2048;
          xconst[(size_t)rowg * 4096 + n] += v;
        }
      }
}

// ---------- two-level grid barrier, r3 protocol (relaxed arrival+poll,
// single release store, wave0-only acquire fence) ----------
// bar[0]=gen, bar[32]=gcnt, bar[64+16x]=xcnt[x] (x = blk&7: XCD-local chain).
__device__ __forceinline__ void grid_barrier(unsigned* __restrict__ bar, unsigned step){
  __threadfence();            // release: every thread drains its h stores
  __syncthreads();
  if (threadIdx.x == 0){
    unsigned x = (unsigned)blockIdx.x & 7u;
    unsigned* xcnt = bar + 64 + 16 * x;
    unsigned* gcnt = bar + 32;
    unsigned* gen  = bar;
    if (__hip_atomic_fetch_add(xcnt, 1u, __ATOMIC_RELAXED, __HIP_MEMORY_SCOPE_AGENT) == 31u){
      __hip_atomic_store(xcnt, 0u, __ATOMIC_RELAXED, __HIP_MEMORY_SCOPE_AGENT);
      if (__hip_atomic_fetch_add(gcnt, 1u, __ATOMIC_RELAXED, __HIP_MEMORY_SCOPE_AGENT) == 7u){
        __hip_atomic_store(gcnt, 0u, __ATOMIC_RELAXED, __HIP_MEMORY_SCOPE_AGENT);
        __hip_atomic_store(gen, step + 1u, __ATOMIC_RELEASE, __HIP_MEMORY_SCOPE_AGENT);
      }
    }
    while (__hip_atomic_load(gen, __ATOMIC_RELAXED, __HIP_MEMORY_SCOPE_AGENT) <= step)
      __builtin_amdgcn_s_sleep(2);
    __threadfence();          // acquire side (r3-proven placement)
  }
  __syncthreads();
}

// ---------- persistent kernel: all 48 LSTM steps (compute verbatim r3/r6) ----------
__global__ __launch_bounds__(256, 1) void k_steps(
    bf16_t* hs,                         // (49, 512, 1024); hs[0]=h0
    const bf16_t* __restrict__ whh,     // (4096, 1024)
    const bf16_t* __restrict__ wlab,    // (4096, 64)
    const bf16_t* __restrict__ labelb,  // (512, 49, 64)
    const float*  __restrict__ xconst,  // (512, 4096)
    const float*  __restrict__ w_ih,    // (4096, 1105), begin col 1040
    const float*  __restrict__ m_init,  // (512, 1024)
    unsigned* __restrict__ bar){
  __shared__ __align__(16) bf16_t sB[64 * 1024];   // 128 KB, swizzled
  __shared__ __align__(16) bf16_t sLab[64 * 64];   // 8 KB, swizzled
  int tid  = threadIdx.x;
  int blk  = blockIdx.x;
  int xcd  = blk & 7;
  int rb   = xcd >> 1;
  int cb   = ((blk >> 3) << 1) | (xcd & 1);
  int lane = tid & 63, w = tid >> 6;
  int l31  = lane & 31;
  int h6   = lane >> 5;
  int b5   = (lane >> 4) & 1;

  // stage resident W slices (swizzled: unit v -> v ^ sw(row), sw = (r ^ r>>3)&7)
  for (int i = tid; i < 8192; i += 256){
    int r = i >> 7, v = i & 127;
    int g = r >> 4, hj = r & 15;
    int sw = (r ^ (r >> 3)) & 7;
    *reinterpret_cast<bf16x8*>(sB + r * 1024 + (v ^ sw) * 8) =
      *reinterpret_cast<const bf16x8*>(whh + (size_t)(g * 1024 + cb * 16 + hj) * 1024 + v * 8);
  }
  for (int i = tid; i < 512; i += 256){
    int r = i >> 3, v = i & 7;
    int g = r >> 4, hj = r & 15;
    int sw = (r ^ (r >> 3)) & 7;
    *reinterpret_cast<bf16x8*>(sLab + r * 64 + (v ^ sw) * 8) =
      *reinterpret_cast<const bf16x8*>(wlab + (size_t)(g * 1024 + cb * 16 + hj) * 64 + v * 8);
  }

  // per-lane constants
  int hcolG = cb * 16 + (lane & 15);
  int row0w = rb * 128 + w * 32;
  float xc[4][8], mreg[8], wb[4];
  #pragma unroll
  for (int g = 0; g < 4; ++g)
    wb[g] = w_ih[(size_t)(g * 1024 + hcolG) * DINn + 1040];
  #pragma unroll
  for (int qi = 0; qi < 8; ++qi){
    int row_l = (qi & 3) + 8 * (qi >> 2) + 16 * b5 + 4 * h6;
    int rowG  = row0w + row_l;
    mreg[qi] = m_init[(size_t)rowG * 1024 + hcolG];
    #pragma unroll
    for (int g = 0; g < 4; ++g)
      xc[g][qi] = xconst[(size_t)rowG * 4096 + g * 1024 + hcolG];
  }
  __syncthreads();

  // LDS read bases + per-frag swizzle keys (sw(row+32) = sw(row)^4)
  int sw0 = (l31 ^ (l31 >> 3)) & 7;
  int sw1 = sw0 ^ 4;
  const bf16_t* sb0 = sB + (size_t)l31 * 1024;
  const bf16_t* sb1 = sB + (size_t)(32 + l31) * 1024;
  const bf16_t* sl0 = sLab + (size_t)l31 * 64;
  const bf16_t* sl1 = sLab + (size_t)(32 + l31) * 64;
  const bf16_t* aBase = hs + (size_t)(row0w + l31) * Hn + h6 * 8;
  const bf16_t* lBase = labelb + (size_t)(row0w + l31) * (Sn * Ln) + h6 * 8;

  for (int t = 0; t < Tn; ++t){
    const bf16_t* aptr = aBase + (size_t)t * (Bn * Hn);
    f32x16 acc[2] = {};
    #pragma unroll 4
    for (int kt = 0; kt < 16; ++kt){
      int kb = kt * 64;
      bf16x8 a[4], b0[4], b1[4];
      #pragma unroll
      for (int ks = 0; ks < 4; ++ks){
        a[ks]  = *reinterpret_cast<const bf16x8*>(aptr + kb + ks * 16);
        int u  = kt * 8 + ks * 2 + h6;
        b0[ks] = *reinterpret_cast<const bf16x8*>(sb0 + (u ^ sw0) * 8);
        b1[ks] = *reinterpret_cast<const bf16x8*>(sb1 + (u ^ sw1) * 8);
      }
      #pragma unroll
      for (int ks = 0; ks < 4; ++ks){
        acc[0] = __builtin_amdgcn_mfma_f32_32x32x16_bf16(a[ks], b0[ks], acc[0], 0, 0, 0);
        acc[1] = __builtin_amdgcn_mfma_f32_32x32x16_bf16(a[ks], b1[ks], acc[1], 0, 0, 0);
      }
    }
    if (t > 0){
      const bf16_t* lp = lBase + (size_t)(t - 1) * 64;
      bf16x8 a[4], b0[4], b1[4];
      #pragma unroll
      for (int ks = 0; ks < 4; ++ks){
        a[ks]  = *reinterpret_cast<const bf16x8*>(lp + ks * 16);
        int u  = ks * 2 + h6;
        b0[ks] = *reinterpret_cast<const bf16x8*>(sl0 + (u ^ sw0) * 8);
        b1[ks] = *reinterpret_cast<const bf16x8*>(sl1 + (u ^ sw1) * 8);
      }
      #pragma unroll
      for (int ks = 0; ks < 4; ++ks){
        acc[0] = __builtin_amdgcn_mfma_f32_32x32x16_bf16(a[ks], b0[ks], acc[0], 0, 0, 0);
        acc[1] = __builtin_amdgcn_mfma_f32_32x32x16_bf16(a[ks], b1[ks], acc[1], 0, 0, 0);
      }
    }

    // gate exchange: partner lane^16 holds the other two gates for same (rows, hcol)
    float oth0[16], oth1[16];
    #pragma unroll
    for (int q = 0; q < 16; ++q){
      oth0[q] = __shfl_xor(acc[0][q], 16, 64);
      oth1[q] = __shfl_xor(acc[1][q], 16, 64);
    }
    bf16_t* hO = hs + (size_t)(t + 1) * (Bn * Hn);
    #pragma unroll
    for (int qi = 0; qi < 8; ++qi){
      float v0, v1, v2, v3;
      if (b5 == 0){ v0 = acc[0][qi];   v1 = oth0[qi];   v2 = acc[1][qi];   v3 = oth1[qi]; }
      else        { v0 = oth0[qi + 8]; v1 = acc[0][qi + 8]; v2 = oth1[qi + 8]; v3 = acc[1][qi + 8]; }
      float gi = v0 + xc[0][qi];
      float gf = v1 + xc[1][qi];
      float gg = v2 + xc[2][qi];
      float go = v3 + xc[3][qi];
      if (t == 0){ gi += wb[0]; gf += wb[1]; gg += wb[2]; go += wb[3]; }
      float mn = sigm(gf) * mreg[qi] + sigm(gi) * tanhf(gg);
      mreg[qi] = mn;
      float hn = sigm(go) * tanhf(mn);
      int row_l = (qi & 3) + 8 * (qi >> 2) + 16 * b5 + 4 * h6;
      hO[(size_t)(row0w + row_l) * 1024 + hcolG] = (bf16_t)hn;
    }
    if (t < Tn - 1)
      grid_barrier(bar, (unsigned)t);
  }
}

// ---------- batched out GEMM + activations + mask + scatter ----------
__global__ __launch_bounds__(256) void k_out(
    const bf16_t* __restrict__ h,      // hs + 512*1024: 24576 x 1024
    const bf16_t* __restrict__ fcwb,
    const float* __restrict__ fc_b, const int* __restrict__ length,
    float* __restrict__ out){
  __shared__ __align__(16) unsigned char smem[(BM + 128) * LDSP * 2];
  bf16_t* sA = (bf16_t*)smem;
  bf16_t* sB = (bf16_t*)(smem + BM * LDSP * 2);
  int tid = threadIdx.x;
  int cb = blockIdx.x, rb = blockIdx.y;
  f32x4 acc[4][2] = {};
  int lane = tid & 63, w = tid >> 6;
  for (int kt = 0; kt < 16; ++kt){
    stageA(sA, h + (size_t)(rb * 64) * 1024 + kt * 64, 1024, tid);
    #pragma unroll
    for (int i = 0; i < 4; ++i){
      int idx = tid + i * 256;
      int r = idx >> 3, v = idx & 7;
      int n = cb * 128 + r;
      bf16x8 val = {};
      if (n < NOn)
        val = *reinterpret_cast<const bf16x8*>(fcwb + (size_t)n * 1024 + kt * 64 + v * 8);
      *reinterpret_cast<bf16x8*>(sB + r * LDSP + v * 8) = val;
    }
    __syncthreads();
    mma_tile(sA, sB, acc, lane, w);
    __syncthreads();
  }
  int lr = lane & 15, lg = lane >> 4;
  #pragma unroll
  for (int mi = 0; mi < 4; ++mi)
    #pragma unroll
    for (int ni = 0; ni < 2; ++ni)
      #pragma unroll
      for (int r = 0; r < 4; ++r){
        int ng = cb * 128 + w * 32 + ni * 16 + lr;
        if (ng >= NOn) continue;
        int rg = rb * 64 + mi * 16 + lg * 4 + r;
        int tt = rg >> 9, b = rg & 511;
        float v = acc[mi][ni][r] + fc_b[ng];
        float mask = (tt < length[b]) ? 1.0f : 0.0f;
        if      (ng < 64)    out[(size_t)rg * 64 + ng] = sigm(v) * mask;
        else if (ng < 1088)  out[(size_t)1572864 + (size_t)rg * 1024 + (ng - 64)] = fmaxf(v, 0.f) * mask;
        else if (ng == 1088) out[(size_t)26738688 + rg] = sigm(v) * mask;
        else                 out[(size_t)26763264 + rg] = __expf(v) * mask;
      }
}

extern "C" void kernel_launch(void* const* d_in, const int* in_sizes, int n_in,
                              void* d_out, int out_size, void* d_ws, size_t ws_size,
                              hipStream_t stream){
  const float* image  = (const float*)d_in[0];
  const float* vp     = (const float*)d_in[1];
  const float* label  = (const float*)d_in[2];
  const int*   length = (const int*)  d_in[3];
  const float* fc_h_w = (const float*)d_in[4];
  const float* fc_h_b = (const float*)d_in[5];
  const float* fc_m_w = (const float*)d_in[6];
  const float* fc_m_b = (const float*)d_in[7];
  const float* w_ih   = (const float*)d_in[8];
  const float* w_hh   = (const float*)d_in[9];
  const float* b_ih   = (const float*)d_in[10];
  const float* b_hh   = (const float*)d_in[11];
  const float* fc_w   = (const float*)d_in[12];
  const float* fc_b   = (const float*)d_in[13];
  float* out = (float*)d_out;

  char* ws = (char*)d_ws;
  bf16_t* imb    = (bf16_t*)(ws + 0);           // 1 MB
  bf16_t* hs     = (bf16_t*)(ws + 1048576);     // 51.4 MB
  float*  m      = (float*) (ws + 52428800);    // 2 MB
  float*  xconst = (float*) (ws + 54525952);    // 8 MB
  bf16_t* whhb   = (bf16_t*)(ws + 62914560);    // 8 MB
  bf16_t* wimgb  = (bf16_t*)(ws + 71303168);    // 8 MB
  bf16_t* wlabb  = (bf16_t*)(ws + 79691776);    // 0.5 MB
  bf16_t* fchwb  = (bf16_t*)(ws + 80216064);    // 2 MB
  bf16_t* fcmwb  = (bf16_t*)(ws + 82313216);    // 2 MB
  bf16_t* fcwb   = (bf16_t*)(ws + 84410368);    // 2.2 MB
  bf16_t* labelb = (bf16_t*)(ws + 86642688);    // 3.2 MB (ends 89853952)
  unsigned* bar  = (unsigned*)(ws + 89853952);  // 4 KB barrier state

  k_mean   <<<dim3(512),  dim3(256), 0, stream>>>(image, imb);
  k_convert<<<dim3(2048), dim3(256), 0, stream>>>(w_hh, fc_h_w, fc_m_w, fc_w, label, w_ih,
                                                  whhb, fchwb, fcmwb, fcwb, labelb, wimgb, wlabb);
  k_vpc    <<<dim3(8192), dim3(256), 0, stream>>>(w_ih, vp, b_ih, b_hh, xconst, bar);
  k_init_gemm<<<dim3(48, 8), dim3(256), 0, stream>>>(imb, fchwb, fcmwb, wimgb,
                                                     fc_h_b, fc_m_b, hs, m, xconst);

  bf16_t* hs_p = hs;
  const bf16_t* whh_p = whhb;
  const bf16_t* wlab_p = wlabb;
  const bf16_t* labelb_p = labelb;
  const float* xconst_p = xconst;
  const float* wih_p = w_ih;
  const float* m_p = m;
  unsigned* bar_p = bar;
  void* kargs[8] = { (void*)&hs_p, (void*)&whh_p, (void*)&wlab_p, (void*)&labelb_p,
                     (void*)&xconst_p, (void*)&wih_p, (void*)&m_p, (void*)&bar_p };
  (void)hipLaunchCooperativeKernel(reinterpret_cast<void*>(k_steps),
                                   dim3(256), dim3(256), kargs, 0, stream);

  k_out<<<dim3(9, 384), dim3(256), 0, stream>>>(hs + (size_t)512 * 1024, fcwb, fc_b, length, out);
}